// Round 7
// baseline (2153.801 us; speedup 1.0000x reference)
//
#include <hip/hip_runtime.h>
#include <stdint.h>

#define KVOL 27
#define CIN  32
#define COUT 64
#define RB16 16          // output rows per bin (4-bit rowlocal, mean 8 entries/bin)
#define WPG  4           // waves per workgroup (independent; no __syncthreads)
#define TSTRIDE 66       // tile row stride in floats
#define SCAN_CHUNK 4096

typedef __attribute__((ext_vector_type(8))) short bf16x8;
typedef __attribute__((ext_vector_type(4))) float f32x4;
typedef __attribute__((ext_vector_type(4))) uint32_t u32x4;

__device__ __forceinline__ ushort f2bf(float f) {
  uint32_t u = __float_as_uint(f);
  u += 0x7FFFu + ((u >> 16) & 1u);   // RNE
  return (ushort)(u >> 16);
}

__device__ __forceinline__ uint32_t cvtpk(float lo, float hi) {
  uint32_t r;
  asm("v_cvt_pk_bf16_f32 %0, %1, %2" : "=v"(r) : "v"(lo), "v"(hi));
  return r;
}

// ---------------------------------------------------------------------------
// weights fp32 [KVOL][CIN][COUT] -> bf16 B-frag layout kernT[ko][ct][col16][k32]
// (verified rounds 3-6)
// ---------------------------------------------------------------------------
__global__ __launch_bounds__(256) void kern_cvt_kernel(const float* __restrict__ kern,
                                                       ushort* __restrict__ kernT) {
  int tid = blockIdx.x * 256 + threadIdx.x;
  int kc   = tid & 3;
  int colq = (tid >> 2) & 15;
  int ct   = (tid >> 6) & 3;
  int ko   = tid >> 8;
  if (ko >= KVOL) return;
  const float* src = kern + (size_t)ko * CIN * COUT + ct * 16 + colq;
  ushort tmp[8];
#pragma unroll
  for (int j = 0; j < 8; ++j) tmp[j] = f2bf(src[(size_t)(kc * 8 + j) * COUT]);
  ushort* dst = kernT + (((size_t)(ko * 4 + ct) * 16 + colq) * 32 + kc * 8);
#pragma unroll
  for (int j = 0; j < 8; ++j) dst[j] = tmp[j];
}

// ---------------------------------------------------------------------------
// histogram over out-major (block16, k) bins — 2 pairs per thread
// ---------------------------------------------------------------------------
__global__ __launch_bounds__(256) void hist_kernel(const int4* __restrict__ kmap2,
                                                   int* __restrict__ count, int M2) {
  int t = blockIdx.x * 256 + threadIdx.x;
  int k = blockIdx.y;
  if (t < M2) {
    int4 v = kmap2[(size_t)k * M2 + t];
    atomicAdd(&count[(v.y >> 4) * KVOL + k], 1);
    atomicAdd(&count[(v.w >> 4) * KVOL + k], 1);
  }
}

// ---------------------------------------------------------------------------
// scan (3 kernels) — verified rounds 2-6
// ---------------------------------------------------------------------------
__global__ __launch_bounds__(256) void scan_reduce(const int* __restrict__ count,
                                                   int* __restrict__ partial, int nb) {
  __shared__ int ws[4];
  int t = threadIdx.x;
  int base = blockIdx.x * SCAN_CHUNK + t * 16;
  int s = 0;
#pragma unroll
  for (int i = 0; i < 16; ++i) { int idx = base + i; if (idx < nb) s += count[idx]; }
  for (int d = 32; d; d >>= 1) s += __shfl_down(s, d);
  if ((t & 63) == 0) ws[t >> 6] = s;
  __syncthreads();
  if (t == 0) partial[blockIdx.x] = ws[0] + ws[1] + ws[2] + ws[3];
}

__global__ __launch_bounds__(64) void scan_partials(int* __restrict__ partial,
                                                    int nchunks, int* __restrict__ total_out) {
  int lane = threadIdx.x;
  int run = 0;
  for (int base = 0; base < nchunks; base += 64) {
    int i = base + lane;
    int orig = (i < nchunks) ? partial[i] : 0;
    int v = orig;
    for (int d = 1; d < 64; d <<= 1) { int u = __shfl_up(v, d); if (lane >= d) v += u; }
    if (i < nchunks) partial[i] = run + v - orig;
    run += __shfl(v, 63);
  }
  if (lane == 0) *total_out = run;
}

__global__ __launch_bounds__(256) void scan_down(const int* __restrict__ count,
                                                 const int* __restrict__ partial,
                                                 int* __restrict__ start,
                                                 int* __restrict__ cursor, int nb) {
  __shared__ int wsum[4];
  int t = threadIdx.x, blk = blockIdx.x;
  int base = blk * SCAN_CHUNK + t * 16;
  int v[16]; int s = 0;
#pragma unroll
  for (int i = 0; i < 16; ++i) { int idx = base + i; v[i] = (idx < nb) ? count[idx] : 0; s += v[i]; }
  int lane = t & 63, wv = t >> 6;
  int sv = s;
  for (int d = 1; d < 64; d <<= 1) { int u = __shfl_up(sv, d); if (lane >= d) sv += u; }
  if (lane == 63) wsum[wv] = sv;
  __syncthreads();
  int wbase = 0;
  for (int i = 0; i < wv; ++i) wbase += wsum[i];
  int prefix = partial[blk] + wbase + (sv - s);
#pragma unroll
  for (int i = 0; i < 16; ++i) {
    int idx = base + i;
    if (idx < nb) { start[idx] = prefix; cursor[idx] = prefix; }
    prefix += v[i];
  }
}

// ---------------------------------------------------------------------------
// scatter into out-major bins: entry = in_idx(18b) | rowlocal(4b)<<18
// ---------------------------------------------------------------------------
__global__ __launch_bounds__(256) void scatter_kernel(const int4* __restrict__ kmap2,
                                                      int* __restrict__ cursor,
                                                      uint32_t* __restrict__ binned, int M2) {
  int t = blockIdx.x * 256 + threadIdx.x;
  int k = blockIdx.y;
  if (t < M2) {
    int4 v = kmap2[(size_t)k * M2 + t];
    int p1 = atomicAdd(&cursor[(v.y >> 4) * KVOL + k], 1);
    binned[p1] = (uint32_t)v.x | ((uint32_t)(v.y & 15) << 18);
    int p2 = atomicAdd(&cursor[(v.w >> 4) * KVOL + k], 1);
    binned[p2] = (uint32_t)v.z | ((uint32_t)(v.w & 15) << 18);
  }
}

// ---------------------------------------------------------------------------
// main: 1 wave per 16 output rows; 27 contiguous bins (out-major) per wave.
// 3-stage pipeline: E(k+2) entry load || F(k+1) shfl rl/cb + feat gather ||
// C(k) cvt_pk -> 4x MFMA -> 16 fire-and-forget ds_add. No drains, no barriers.
// ---------------------------------------------------------------------------
__global__ __launch_bounds__(256) void conv_mfma5(
    const float* __restrict__ feat,       // [N][CIN] f32
    const uint32_t* __restrict__ binned,  // [E] out-major
    const int* __restrict__ start,        // [NBIN+1]
    const ushort* __restrict__ kernT,     // [KVOL][4][16][32] bf16
    const float* __restrict__ bias,       // [COUT]
    float* __restrict__ out) {            // [N][COUT]
  __shared__ float tile[WPG][RB16][TSTRIDE];
  const int wv = threadIdx.x >> 6;
  const int l  = threadIdx.x & 63;
  const int q  = l & 15;          // entry slot / cout-within-tile
  const int g  = l >> 4;          // feat chunk / D row group
  const int blk = blockIdx.x * WPG + wv;

  // zero my wave's tile (plain LDS stores)
  {
    const float2 z2 = {0.f, 0.f};
    float2* zp = (float2*)&tile[wv][0][0];
    for (int i = l; i < RB16 * TSTRIDE / 2; i += 64) zp[i] = z2;
  }

  // segment bounds: lane j (j<28) holds start[blk*27 + j]
  int sv = 0;
  if (l < KVOL + 1) sv = start[blk * KVOL + l];

#define ESTAGE(KK, E) do {                                                     \
    int sbE_ = __shfl(sv, (KK));                                               \
    int cnE_ = __shfl(sv, (KK) + 1) - sbE_;                                    \
    E = 0u;                                                                    \
    if (cnE_ > 0) {                                                            \
      int cbE_ = cnE_ < 16 ? cnE_ : 16;                                        \
      E = binned[sbE_ + (q < cbE_ ? q : 0)];                                   \
    }                                                                          \
  } while (0)

#define FSTAGE(KK, E, F0, F1, RL0, RL1, RL2, RL3, CB) do {                     \
    int cnF_ = __shfl(sv, (KK) + 1) - __shfl(sv, (KK));                        \
    CB = cnF_ < 16 ? cnF_ : 16;                                                \
    const float* fpF_ = feat + (size_t)((E) & 0x3FFFFu) * CIN + g * 8;         \
    F0 = *(const float4*)fpF_;                                                 \
    F1 = *(const float4*)(fpF_ + 4);                                           \
    RL0 = (__shfl((int)(E), 4 * g + 0) >> 18) & 15;                            \
    RL1 = (__shfl((int)(E), 4 * g + 1) >> 18) & 15;                            \
    RL2 = (__shfl((int)(E), 4 * g + 2) >> 18) & 15;                            \
    RL3 = (__shfl((int)(E), 4 * g + 3) >> 18) & 15;                            \
  } while (0)

#define CBODY(KK, CB, A_, RL0, RL1, RL2, RL3) do {                             \
    const ushort* kb_ = kernT + ((size_t)(KK) * 64 + q) * 32 + g * 8;          \
    bf16x8 b0_ = *(const bf16x8*)(kb_);                                        \
    bf16x8 b1_ = *(const bf16x8*)(kb_ + 512);                                  \
    bf16x8 b2_ = *(const bf16x8*)(kb_ + 1024);                                 \
    bf16x8 b3_ = *(const bf16x8*)(kb_ + 1536);                                 \
    f32x4 z_ = {0.f, 0.f, 0.f, 0.f};                                           \
    f32x4 c0_ = __builtin_amdgcn_mfma_f32_16x16x32_bf16(A_, b0_, z_, 0, 0, 0); \
    f32x4 c1_ = __builtin_amdgcn_mfma_f32_16x16x32_bf16(A_, b1_, z_, 0, 0, 0); \
    f32x4 c2_ = __builtin_amdgcn_mfma_f32_16x16x32_bf16(A_, b2_, z_, 0, 0, 0); \
    f32x4 c3_ = __builtin_amdgcn_mfma_f32_16x16x32_bf16(A_, b3_, z_, 0, 0, 0); \
    atomicAdd(&tile[wv][RL0][q],      c0_[0]);                                 \
    atomicAdd(&tile[wv][RL0][q + 16], c1_[0]);                                 \
    atomicAdd(&tile[wv][RL0][q + 32], c2_[0]);                                 \
    atomicAdd(&tile[wv][RL0][q + 48], c3_[0]);                                 \
    atomicAdd(&tile[wv][RL1][q],      c0_[1]);                                 \
    atomicAdd(&tile[wv][RL1][q + 16], c1_[1]);                                 \
    atomicAdd(&tile[wv][RL1][q + 32], c2_[1]);                                 \
    atomicAdd(&tile[wv][RL1][q + 48], c3_[1]);                                 \
    atomicAdd(&tile[wv][RL2][q],      c0_[2]);                                 \
    atomicAdd(&tile[wv][RL2][q + 16], c1_[2]);                                 \
    atomicAdd(&tile[wv][RL2][q + 32], c2_[2]);                                 \
    atomicAdd(&tile[wv][RL2][q + 48], c3_[2]);                                 \
    atomicAdd(&tile[wv][RL3][q],      c0_[3]);                                 \
    atomicAdd(&tile[wv][RL3][q + 16], c1_[3]);                                 \
    atomicAdd(&tile[wv][RL3][q + 32], c2_[3]);                                 \
    atomicAdd(&tile[wv][RL3][q + 48], c3_[3]);                                 \
  } while (0)

#define CSTAGE(KK, F0, F1, RL0, RL1, RL2, RL3, CB) do {                        \
    if (CB > 0) {                                                              \
      u32x4 ua_;                                                               \
      ua_.x = cvtpk(F0.x, F0.y); ua_.y = cvtpk(F0.z, F0.w);                    \
      ua_.z = cvtpk(F1.x, F1.y); ua_.w = cvtpk(F1.z, F1.w);                    \
      if (q >= CB) { ua_.x = 0; ua_.y = 0; ua_.z = 0; ua_.w = 0; }             \
      bf16x8 a_ = __builtin_bit_cast(bf16x8, ua_);                             \
      CBODY(KK, CB, a_, RL0, RL1, RL2, RL3);                                   \
      /* rare tail: cnt > 16 (P ~ 0.4%) */                                     \
      int sbT_ = __shfl(sv, (KK));                                             \
      int cnT_ = __shfl(sv, (KK) + 1) - sbT_;                                  \
      for (int baseT_ = 16; baseT_ < cnT_; baseT_ += 16) {                     \
        int cbT_ = cnT_ - baseT_; if (cbT_ > 16) cbT_ = 16;                    \
        uint32_t eT_ = binned[sbT_ + baseT_ + (q < cbT_ ? q : 0)];             \
        const float* fpT_ = feat + (size_t)(eT_ & 0x3FFFFu) * CIN + g * 8;     \
        float4 h0_ = *(const float4*)fpT_;                                     \
        float4 h1_ = *(const float4*)(fpT_ + 4);                               \
        int tr0_ = (__shfl((int)eT_, 4 * g + 0) >> 18) & 15;                   \
        int tr1_ = (__shfl((int)eT_, 4 * g + 1) >> 18) & 15;                   \
        int tr2_ = (__shfl((int)eT_, 4 * g + 2) >> 18) & 15;                   \
        int tr3_ = (__shfl((int)eT_, 4 * g + 3) >> 18) & 15;                   \
        u32x4 ub_;                                                             \
        ub_.x = cvtpk(h0_.x, h0_.y); ub_.y = cvtpk(h0_.z, h0_.w);              \
        ub_.z = cvtpk(h1_.x, h1_.y); ub_.w = cvtpk(h1_.z, h1_.w);              \
        if (q >= cbT_) { ub_.x = 0; ub_.y = 0; ub_.z = 0; ub_.w = 0; }         \
        bf16x8 a2_ = __builtin_bit_cast(bf16x8, ub_);                          \
        CBODY(KK, cbT_, a2_, tr0_, tr1_, tr2_, tr3_);                          \
      }                                                                        \
    }                                                                          \
  } while (0)

  uint32_t eA = 0, eB = 0;
  float4 fA0, fA1, fB0, fB1;
  int rlA0, rlA1, rlA2, rlA3, cbA;
  int rlB0, rlB1, rlB2, rlB3, cbB;

  // prologue
  ESTAGE(0, eA);
  ESTAGE(1, eB);
  FSTAGE(0, eA, fA0, fA1, rlA0, rlA1, rlA2, rlA3, cbA);

  for (int kk = 0; kk < KVOL - 1; kk += 2) {
    ESTAGE(kk + 2, eA);                                       // e for kk+2
    FSTAGE(kk + 1, eB, fB0, fB1, rlB0, rlB1, rlB2, rlB3, cbB);
    CSTAGE(kk, fA0, fA1, rlA0, rlA1, rlA2, rlA3, cbA);
    ESTAGE(kk + 3, eB);                                       // e for kk+3 (degenerate past 26)
    FSTAGE(kk + 2, eA, fA0, fA1, rlA0, rlA1, rlA2, rlA3, cbA);
    CSTAGE(kk + 1, fB0, fB1, rlB0, rlB1, rlB2, rlB3, cbB);
  }
  CSTAGE(KVOL - 1, fA0, fA1, rlA0, rlA1, rlA2, rlA3, cbA);

  // epilogue: wave-private tile, LDS ops in-order -> no barrier needed
  const float bv = bias[l];
  const int R0 = blk * RB16;
#pragma unroll
  for (int r = 0; r < RB16; ++r)
    out[(size_t)(R0 + r) * COUT + l] = tile[wv][r][l] + bv;
}

// ---------------------------------------------------------------------------
extern "C" void kernel_launch(void* const* d_in, const int* in_sizes, int n_in,
                              void* d_out, int out_size, void* d_ws, size_t ws_size,
                              hipStream_t stream) {
  const float* feat  = (const float*)d_in[0];
  const int4*  kmap2 = (const int4*)d_in[3];   // 2 pairs per int4
  const float* kern  = (const float*)d_in[4];
  const float* bias  = (const float*)d_in[5];
  float* out = (float*)d_out;

  const int N = in_sizes[0] / CIN;            // 200000
  const int M = in_sizes[3] / (2 * KVOL);     // 100000
  const int M2 = M / 2;                       // 50000
  const int NB = N / RB16;                    // 12500
  const int NBIN = NB * KVOL;                 // 337500

  // workspace
  ushort* kernT = (ushort*)d_ws;                        // 55296 ushorts
  int* count    = (int*)(kernT + (size_t)KVOL * CIN * COUT);
  int* startA   = count + NBIN;                         // NBIN+1
  int* cursor   = startA + NBIN + 1;
  int* partial  = cursor + NBIN;                        // 128
  uint32_t* binned = (uint32_t*)(partial + 128);        // KVOL*M

  const int nchunks = (NBIN + SCAN_CHUNK - 1) / SCAN_CHUNK;   // 83

  hipMemsetAsync(count, 0, (size_t)NBIN * sizeof(int), stream);
  hipLaunchKernelGGL(kern_cvt_kernel, dim3(KVOL), dim3(256), 0, stream, kern, kernT);

  dim3 pgrid((M2 + 255) / 256, KVOL);
  hipLaunchKernelGGL(hist_kernel, pgrid, dim3(256), 0, stream, kmap2, count, M2);
  hipLaunchKernelGGL(scan_reduce, dim3(nchunks), dim3(256), 0, stream, count, partial, NBIN);
  hipLaunchKernelGGL(scan_partials, dim3(1), dim3(64), 0, stream, partial, nchunks, startA + NBIN);
  hipLaunchKernelGGL(scan_down, dim3(nchunks), dim3(256), 0, stream,
                     count, partial, startA, cursor, NBIN);
  hipLaunchKernelGGL(scatter_kernel, pgrid, dim3(256), 0, stream, kmap2, cursor, binned, M2);

  hipLaunchKernelGGL(conv_mfma5, dim3(NB / WPG), dim3(256), 0, stream,
                     feat, binned, startA, kernT, bias, out);
}

// Round 8
// 1394.560 us; speedup vs baseline: 1.5444x; 1.5444x over previous
//
#include <hip/hip_runtime.h>
#include <stdint.h>

#define KVOL 27
#define CIN  32
#define COUT 64
#define RB   64          // output rows per block (6-bit rowlocal)
#define NWV  9           // waves per workgroup: wave w owns k = 3w..3w+2
#define TSTRIDE 66       // tile row stride in floats
#define SCAN_CHUNK 4096

typedef __attribute__((ext_vector_type(8))) short bf16x8;
typedef __attribute__((ext_vector_type(4))) float f32x4;
typedef __attribute__((ext_vector_type(4))) uint32_t u32x4;

__device__ __forceinline__ ushort f2bf(float f) {
  uint32_t u = __float_as_uint(f);
  u += 0x7FFFu + ((u >> 16) & 1u);   // RNE
  return (ushort)(u >> 16);
}

__device__ __forceinline__ uint32_t cvtpk(float lo, float hi) {
  uint32_t r;
  asm("v_cvt_pk_bf16_f32 %0, %1, %2" : "=v"(r) : "v"(lo), "v"(hi));
  return r;
}

// ---------------------------------------------------------------------------
// weights fp32 [KVOL][CIN][COUT] -> bf16 B-frag layout kernT[ko][ct][col16][k32]
// (verified rounds 3-7)
// ---------------------------------------------------------------------------
__global__ __launch_bounds__(256) void kern_cvt_kernel(const float* __restrict__ kern,
                                                       ushort* __restrict__ kernT) {
  int tid = blockIdx.x * 256 + threadIdx.x;
  int kc   = tid & 3;
  int colq = (tid >> 2) & 15;
  int ct   = (tid >> 6) & 3;
  int ko   = tid >> 8;
  if (ko >= KVOL) return;
  const float* src = kern + (size_t)ko * CIN * COUT + ct * 16 + colq;
  ushort tmp[8];
#pragma unroll
  for (int j = 0; j < 8; ++j) tmp[j] = f2bf(src[(size_t)(kc * 8 + j) * COUT]);
  ushort* dst = kernT + (((size_t)(ko * 4 + ct) * 16 + colq) * 32 + kc * 8);
#pragma unroll
  for (int j = 0; j < 8; ++j) dst[j] = tmp[j];
}

// ---------------------------------------------------------------------------
// histogram over k-major (k, block64) bins — 2 pairs per thread
// ---------------------------------------------------------------------------
__global__ __launch_bounds__(256) void hist_kernel(const int4* __restrict__ kmap2,
                                                   int* __restrict__ count,
                                                   int M2, int NB) {
  int t = blockIdx.x * 256 + threadIdx.x;
  int k = blockIdx.y;
  if (t < M2) {
    int4 v = kmap2[(size_t)k * M2 + t];
    atomicAdd(&count[k * NB + (v.y >> 6)], 1);
    atomicAdd(&count[k * NB + (v.w >> 6)], 1);
  }
}

// ---------------------------------------------------------------------------
// scan (3 kernels) — verified rounds 2-7
// ---------------------------------------------------------------------------
__global__ __launch_bounds__(256) void scan_reduce(const int* __restrict__ count,
                                                   int* __restrict__ partial, int nb) {
  __shared__ int ws[4];
  int t = threadIdx.x;
  int base = blockIdx.x * SCAN_CHUNK + t * 16;
  int s = 0;
#pragma unroll
  for (int i = 0; i < 16; ++i) { int idx = base + i; if (idx < nb) s += count[idx]; }
  for (int d = 32; d; d >>= 1) s += __shfl_down(s, d);
  if ((t & 63) == 0) ws[t >> 6] = s;
  __syncthreads();
  if (t == 0) partial[blockIdx.x] = ws[0] + ws[1] + ws[2] + ws[3];
}

__global__ __launch_bounds__(64) void scan_partials(int* __restrict__ partial,
                                                    int nchunks, int* __restrict__ total_out) {
  int lane = threadIdx.x;
  int run = 0;
  for (int base = 0; base < nchunks; base += 64) {
    int i = base + lane;
    int orig = (i < nchunks) ? partial[i] : 0;
    int v = orig;
    for (int d = 1; d < 64; d <<= 1) { int u = __shfl_up(v, d); if (lane >= d) v += u; }
    if (i < nchunks) partial[i] = run + v - orig;
    run += __shfl(v, 63);
  }
  if (lane == 0) *total_out = run;
}

__global__ __launch_bounds__(256) void scan_down(const int* __restrict__ count,
                                                 const int* __restrict__ partial,
                                                 int* __restrict__ start,
                                                 int* __restrict__ cursor, int nb) {
  __shared__ int wsum[4];
  int t = threadIdx.x, blk = blockIdx.x;
  int base = blk * SCAN_CHUNK + t * 16;
  int v[16]; int s = 0;
#pragma unroll
  for (int i = 0; i < 16; ++i) { int idx = base + i; v[i] = (idx < nb) ? count[idx] : 0; s += v[i]; }
  int lane = t & 63, wv = t >> 6;
  int sv = s;
  for (int d = 1; d < 64; d <<= 1) { int u = __shfl_up(sv, d); if (lane >= d) sv += u; }
  if (lane == 63) wsum[wv] = sv;
  __syncthreads();
  int wbase = 0;
  for (int i = 0; i < wv; ++i) wbase += wsum[i];
  int prefix = partial[blk] + wbase + (sv - s);
#pragma unroll
  for (int i = 0; i < 16; ++i) {
    int idx = base + i;
    if (idx < nb) { start[idx] = prefix; cursor[idx] = prefix; }
    prefix += v[i];
  }
}

// ---------------------------------------------------------------------------
// scatter into k-major bins: entry = in_idx(18b) | rowlocal(6b)<<18
// writes confined to this k's 400KB partition
// ---------------------------------------------------------------------------
__global__ __launch_bounds__(256) void scatter_kernel(const int4* __restrict__ kmap2,
                                                      int* __restrict__ cursor,
                                                      uint32_t* __restrict__ binned,
                                                      int M2, int NB) {
  int t = blockIdx.x * 256 + threadIdx.x;
  int k = blockIdx.y;
  if (t < M2) {
    int4 v = kmap2[(size_t)k * M2 + t];
    int p1 = atomicAdd(&cursor[k * NB + (v.y >> 6)], 1);
    binned[p1] = (uint32_t)v.x | ((uint32_t)(v.y & 63) << 18);
    int p2 = atomicAdd(&cursor[k * NB + (v.w >> 6)], 1);
    binned[p2] = (uint32_t)v.z | ((uint32_t)(v.w & 63) << 18);
  }
}

// ---------------------------------------------------------------------------
// main: 1 workgroup (9 waves) per 64 output rows; wave w owns k = 3w..3w+2.
// Per bin, per 16-entry batch:
//   each lane loads ITS OWN entry word (one 64B line) -> own feat chunk gather
//   (no cross-lane on the address path), cvt_pk -> 4x mfma_16x16x32_bf16 from
//   zero -> 4 post-compute shfl for row targets -> 16 fire-and-forget ds_add
//   into the block-shared [64][66] tile. Latency hidden by 27 waves/CU (TLP),
//   not in-wave pipelining. Rolled loops -> compact code.
// ---------------------------------------------------------------------------
__global__ __launch_bounds__(NWV * 64) void conv_mfma6(
    const float* __restrict__ feat,       // [N][CIN] f32
    const uint32_t* __restrict__ binned,  // [E] k-major
    const int* __restrict__ start,        // [NBIN+1] k-major
    const ushort* __restrict__ kernT,     // [KVOL][4][16][32] bf16
    const float* __restrict__ bias,       // [COUT]
    float* __restrict__ out,              // [N][COUT]
    int NB) {                             // blocks per k (N/RB)
  __shared__ float tile[RB][TSTRIDE];     // 16.9 KB, shared by all 9 waves
  const int wv = threadIdx.x >> 6;        // 0..8 -> k group
  const int l  = threadIdx.x & 63;
  const int q  = l & 15;          // entry slot / cout-within-tile
  const int g  = l >> 4;          // feat chunk / D row group
  const int blk = blockIdx.x;

  for (int i = threadIdx.x; i < RB * TSTRIDE; i += NWV * 64)
    ((float*)tile)[i] = 0.f;

  // segment bounds for my 3 bins: lane l<6 loads start[(3wv + l>>1)*NB + blk + (l&1)]
  int sb = 0;
  if (l < 6) sb = start[(3 * wv + (l >> 1)) * NB + blk + (l & 1)];
  const int s0 = __shfl(sb, 0), e0 = __shfl(sb, 1);
  const int s1 = __shfl(sb, 2), e1 = __shfl(sb, 3);
  const int s2 = __shfl(sb, 4), e2 = __shfl(sb, 5);

  __syncthreads();   // tile zeroed before any ds_add

#pragma unroll
  for (int t = 0; t < 3; ++t) {
    const int k   = 3 * wv + t;
    const int sbt = (t == 0) ? s0 : (t == 1) ? s1 : s2;
    const int set = (t == 0) ? e0 : (t == 1) ? e1 : e2;
    const int cnt = set - sbt;
    if (cnt <= 0) continue;

    // W[k] B-fragments (L2-resident, 4x16B), held across this bin's batches
    const ushort* kb = kernT + ((size_t)k * 64 + q) * 32 + g * 8;
    const bf16x8 b0 = *(const bf16x8*)(kb);
    const bf16x8 b1 = *(const bf16x8*)(kb + 512);
    const bf16x8 b2 = *(const bf16x8*)(kb + 1024);
    const bf16x8 b3 = *(const bf16x8*)(kb + 1536);

    for (int base = 0; base < cnt; base += 16) {
      int cb = cnt - base; if (cb > 16) cb = 16;

      // own entry word: lanes with same q read same word; 16 words = one line
      uint32_t e = binned[sbt + base + (q < cb ? q : cb - 1)];

      // own feat chunk: lane (q,g) reads feat[in(entry q)][8g..8g+8)
      const float* fp = feat + (size_t)(e & 0x3FFFFu) * CIN + g * 8;
      float4 f0 = *(const float4*)fp;
      float4 f1 = *(const float4*)(fp + 4);
      u32x4 ua;
      ua.x = cvtpk(f0.x, f0.y); ua.y = cvtpk(f0.z, f0.w);
      ua.z = cvtpk(f1.x, f1.y); ua.w = cvtpk(f1.z, f1.w);
      if (q >= cb) { ua.x = 0; ua.y = 0; ua.z = 0; ua.w = 0; }  // pad rows -> 0
      bf16x8 a = __builtin_bit_cast(bf16x8, ua);

      f32x4 z = {0.f, 0.f, 0.f, 0.f};
      f32x4 c0 = __builtin_amdgcn_mfma_f32_16x16x32_bf16(a, b0, z, 0, 0, 0);
      f32x4 c1 = __builtin_amdgcn_mfma_f32_16x16x32_bf16(a, b1, z, 0, 0, 0);
      f32x4 c2 = __builtin_amdgcn_mfma_f32_16x16x32_bf16(a, b2, z, 0, 0, 0);
      f32x4 c3 = __builtin_amdgcn_mfma_f32_16x16x32_bf16(a, b3, z, 0, 0, 0);

      // post-compute routing: entry j held by lane j (j<16); pad rows add 0.0
      int rl0 = ((uint32_t)__shfl((int)e, 4 * g + 0) >> 18) & 63;
      int rl1 = ((uint32_t)__shfl((int)e, 4 * g + 1) >> 18) & 63;
      int rl2 = ((uint32_t)__shfl((int)e, 4 * g + 2) >> 18) & 63;
      int rl3 = ((uint32_t)__shfl((int)e, 4 * g + 3) >> 18) & 63;

      atomicAdd(&tile[rl0][q],      c0[0]); atomicAdd(&tile[rl0][q + 16], c1[0]);
      atomicAdd(&tile[rl0][q + 32], c2[0]); atomicAdd(&tile[rl0][q + 48], c3[0]);
      atomicAdd(&tile[rl1][q],      c0[1]); atomicAdd(&tile[rl1][q + 16], c1[1]);
      atomicAdd(&tile[rl1][q + 32], c2[1]); atomicAdd(&tile[rl1][q + 48], c3[1]);
      atomicAdd(&tile[rl2][q],      c0[2]); atomicAdd(&tile[rl2][q + 16], c1[2]);
      atomicAdd(&tile[rl2][q + 32], c2[2]); atomicAdd(&tile[rl2][q + 48], c3[2]);
      atomicAdd(&tile[rl3][q],      c0[3]); atomicAdd(&tile[rl3][q + 16], c1[3]);
      atomicAdd(&tile[rl3][q + 32], c2[3]); atomicAdd(&tile[rl3][q + 48], c3[3]);
    }
  }

  __syncthreads();   // all waves' ds_adds done

  // writeout: lane = cout channel, wave-strided rows; 256B coalesced stores
  const float bv = bias[l];
  const int R0 = blk * RB;
  for (int r = wv; r < RB; r += NWV)
    out[(size_t)(R0 + r) * COUT + l] = tile[r][l] + bv;
}

// ---------------------------------------------------------------------------
extern "C" void kernel_launch(void* const* d_in, const int* in_sizes, int n_in,
                              void* d_out, int out_size, void* d_ws, size_t ws_size,
                              hipStream_t stream) {
  const float* feat  = (const float*)d_in[0];
  const int4*  kmap2 = (const int4*)d_in[3];   // 2 pairs per int4
  const float* kern  = (const float*)d_in[4];
  const float* bias  = (const float*)d_in[5];
  float* out = (float*)d_out;

  const int N = in_sizes[0] / CIN;            // 200000
  const int M = in_sizes[3] / (2 * KVOL);     // 100000
  const int M2 = M / 2;                       // 50000
  const int NB = N / RB;                      // 3125
  const int NBIN = NB * KVOL;                 // 84375

  // workspace
  ushort* kernT = (ushort*)d_ws;                        // 55296 ushorts
  int* count    = (int*)(kernT + (size_t)KVOL * CIN * COUT);
  int* startA   = count + NBIN;                         // NBIN+1
  int* cursor   = startA + NBIN + 1;
  int* partial  = cursor + NBIN;                        // 64
  uint32_t* binned = (uint32_t*)(partial + 64);         // KVOL*M

  const int nchunks = (NBIN + SCAN_CHUNK - 1) / SCAN_CHUNK;   // 21

  hipMemsetAsync(count, 0, (size_t)NBIN * sizeof(int), stream);
  hipLaunchKernelGGL(kern_cvt_kernel, dim3(KVOL), dim3(256), 0, stream, kern, kernT);

  dim3 pgrid((M2 + 255) / 256, KVOL);
  hipLaunchKernelGGL(hist_kernel, pgrid, dim3(256), 0, stream, kmap2, count, M2, NB);
  hipLaunchKernelGGL(scan_reduce, dim3(nchunks), dim3(256), 0, stream, count, partial, NBIN);
  hipLaunchKernelGGL(scan_partials, dim3(1), dim3(64), 0, stream, partial, nchunks, startA + NBIN);
  hipLaunchKernelGGL(scan_down, dim3(nchunks), dim3(256), 0, stream,
                     count, partial, startA, cursor, NBIN);
  hipLaunchKernelGGL(scatter_kernel, pgrid, dim3(256), 0, stream, kmap2, cursor, binned, M2, NB);

  hipLaunchKernelGGL(conv_mfma6, dim3(NB), dim3(NWV * 64), 0, stream,
                     feat, binned, startA, kernT, bias, out, NB);
}

// Round 9
// 810.207 us; speedup vs baseline: 2.6583x; 1.7212x over previous
//
#include <hip/hip_runtime.h>
#include <stdint.h>

#define KVOL 27
#define CIN  32
#define COUT 64
#define RB16 16          // output rows per bin (4-bit rowlocal)
#define WPG  4           // independent waves per workgroup (no __syncthreads)
#define ENTCAP 384       // entries per wave's 27 segments (mean 216, +11 sigma)
#define SCAN_CHUNK 4096

typedef __attribute__((ext_vector_type(8))) short bf16x8;
typedef __attribute__((ext_vector_type(8))) ushort u16x8;
typedef __attribute__((ext_vector_type(4))) float f32x4;

__device__ __forceinline__ ushort f2bf(float f) {
  uint32_t u = __float_as_uint(f);
  u += 0x7FFFu + ((u >> 16) & 1u);   // RNE
  return (ushort)(u >> 16);
}

__device__ __forceinline__ uint32_t cvtpk(float lo, float hi) {
  uint32_t r;
  asm("v_cvt_pk_bf16_f32 %0, %1, %2" : "=v"(r) : "v"(lo), "v"(hi));
  return r;
}

// ---------------------------------------------------------------------------
// feat fp32 -> bf16 rows (64B/row = ONE cache line per gather)  [r3-verified]
// ---------------------------------------------------------------------------
__global__ __launch_bounds__(256) void feat_cvt_kernel(const float* __restrict__ feat,
                                                       ushort* __restrict__ feat16,
                                                       int total4) {
  int i = blockIdx.x * 256 + threadIdx.x;
  if (i < total4) {
    float4 v = ((const float4*)feat)[i];
    ushort4 o;
    o.x = f2bf(v.x); o.y = f2bf(v.y); o.z = f2bf(v.z); o.w = f2bf(v.w);
    ((ushort4*)feat16)[i] = o;
  }
}

// ---------------------------------------------------------------------------
// weights fp32 [KVOL][CIN][COUT] -> bf16 B-frag layout kernT[ko][ct][col16][k32]
// (verified rounds 3-8)
// ---------------------------------------------------------------------------
__global__ __launch_bounds__(256) void kern_cvt_kernel(const float* __restrict__ kern,
                                                       ushort* __restrict__ kernT) {
  int tid = blockIdx.x * 256 + threadIdx.x;
  int kc   = tid & 3;
  int colq = (tid >> 2) & 15;
  int ct   = (tid >> 6) & 3;
  int ko   = tid >> 8;
  if (ko >= KVOL) return;
  const float* src = kern + (size_t)ko * CIN * COUT + ct * 16 + colq;
  ushort tmp[8];
#pragma unroll
  for (int j = 0; j < 8; ++j) tmp[j] = f2bf(src[(size_t)(kc * 8 + j) * COUT]);
  ushort* dst = kernT + (((size_t)(ko * 4 + ct) * 16 + colq) * 32 + kc * 8);
#pragma unroll
  for (int j = 0; j < 8; ++j) dst[j] = tmp[j];
}

// ---------------------------------------------------------------------------
// histogram over k-major (k, block16) bins — 2 pairs per thread
// ---------------------------------------------------------------------------
__global__ __launch_bounds__(256) void hist_kernel(const int4* __restrict__ kmap2,
                                                   int* __restrict__ count,
                                                   int M2, int NB) {
  int t = blockIdx.x * 256 + threadIdx.x;
  int k = blockIdx.y;
  if (t < M2) {
    int4 v = kmap2[(size_t)k * M2 + t];
    atomicAdd(&count[k * NB + (v.y >> 4)], 1);
    atomicAdd(&count[k * NB + (v.w >> 4)], 1);
  }
}

// ---------------------------------------------------------------------------
// scan (3 kernels) — verified rounds 2-8
// ---------------------------------------------------------------------------
__global__ __launch_bounds__(256) void scan_reduce(const int* __restrict__ count,
                                                   int* __restrict__ partial, int nb) {
  __shared__ int ws[4];
  int t = threadIdx.x;
  int base = blockIdx.x * SCAN_CHUNK + t * 16;
  int s = 0;
#pragma unroll
  for (int i = 0; i < 16; ++i) { int idx = base + i; if (idx < nb) s += count[idx]; }
  for (int d = 32; d; d >>= 1) s += __shfl_down(s, d);
  if ((t & 63) == 0) ws[t >> 6] = s;
  __syncthreads();
  if (t == 0) partial[blockIdx.x] = ws[0] + ws[1] + ws[2] + ws[3];
}

__global__ __launch_bounds__(64) void scan_partials(int* __restrict__ partial,
                                                    int nchunks, int* __restrict__ total_out) {
  int lane = threadIdx.x;
  int run = 0;
  for (int base = 0; base < nchunks; base += 64) {
    int i = base + lane;
    int orig = (i < nchunks) ? partial[i] : 0;
    int v = orig;
    for (int d = 1; d < 64; d <<= 1) { int u = __shfl_up(v, d); if (lane >= d) v += u; }
    if (i < nchunks) partial[i] = run + v - orig;
    run += __shfl(v, 63);
  }
  if (lane == 0) *total_out = run;
}

__global__ __launch_bounds__(256) void scan_down(const int* __restrict__ count,
                                                 const int* __restrict__ partial,
                                                 int* __restrict__ start,
                                                 int* __restrict__ cursor, int nb) {
  __shared__ int wsum[4];
  int t = threadIdx.x, blk = blockIdx.x;
  int base = blk * SCAN_CHUNK + t * 16;
  int v[16]; int s = 0;
#pragma unroll
  for (int i = 0; i < 16; ++i) { int idx = base + i; v[i] = (idx < nb) ? count[idx] : 0; s += v[i]; }
  int lane = t & 63, wv = t >> 6;
  int sv = s;
  for (int d = 1; d < 64; d <<= 1) { int u = __shfl_up(sv, d); if (lane >= d) sv += u; }
  if (lane == 63) wsum[wv] = sv;
  __syncthreads();
  int wbase = 0;
  for (int i = 0; i < wv; ++i) wbase += wsum[i];
  int prefix = partial[blk] + wbase + (sv - s);
#pragma unroll
  for (int i = 0; i < 16; ++i) {
    int idx = base + i;
    if (idx < nb) { start[idx] = prefix; cursor[idx] = prefix; }
    prefix += v[i];
  }
}

// ---------------------------------------------------------------------------
// scatter into k-major bins: entry = in_idx(18b) | rowlocal(4b)<<18
// writes confined to this k's ~1.35MB partition (L2-resident window)
// ---------------------------------------------------------------------------
__global__ __launch_bounds__(256) void scatter_kernel(const int4* __restrict__ kmap2,
                                                      int* __restrict__ cursor,
                                                      uint32_t* __restrict__ binned,
                                                      int M2, int NB) {
  int t = blockIdx.x * 256 + threadIdx.x;
  int k = blockIdx.y;
  if (t < M2) {
    int4 v = kmap2[(size_t)k * M2 + t];
    int p1 = atomicAdd(&cursor[k * NB + (v.y >> 4)], 1);
    binned[p1] = (uint32_t)v.x | ((uint32_t)(v.y & 15) << 18);
    int p2 = atomicAdd(&cursor[k * NB + (v.w >> 4)], 1);
    binned[p2] = (uint32_t)v.z | ((uint32_t)(v.w & 15) << 18);
  }
}

// ---------------------------------------------------------------------------
// main: r4's verified structure + bf16 feat (1 line/row gather).
// Per k: STAGE (one k ahead): lane (eidx,part) loads its 16B bf16 chunk of
// entry eidx. CONSUME: unpack -> 8 f32 LDS atomic presum into staging row
// rowlocal -> drain -> A-read+cvt_pk -> 4 MFMA (C accumulates across k) ->
// drain -> rezero buf. Entry list copied to LDS once (27 segment bursts).
// ---------------------------------------------------------------------------
#define STAGE(KK, OFF, CNT, G, RL, VAL) do {                                   \
    OFF = __shfl(excl, (KK));                                                  \
    CNT = __shfl(cnt_l, (KK));                                                 \
    int c0_ = CNT < 16 ? CNT : 16;                                             \
    VAL = (eidx < c0_);                                                        \
    int ix_ = OFF + (VAL ? eidx : 0);                                          \
    if (ix_ >= ENTCAP) ix_ = 0;                                                \
    uint32_t e_ = ents[wv][ix_];                                               \
    RL = (int)((e_ >> 18) & 15u);                                              \
    const ushort* fp_ = feat16 + (size_t)(e_ & 0x3FFFFu) * CIN + part * 8;     \
    if (VAL) G = *(const u16x8*)fp_;                                           \
  } while (0)

#define PRESUM8(G_, RLX, PARTX) do {                                           \
    float* rp_ = sp_ + (RLX) * 36 + (PARTX) * 8;                               \
    _Pragma("unroll")                                                          \
    for (int j_ = 0; j_ < 8; ++j_) {                                           \
      float fv_ = __uint_as_float((uint32_t)(ushort)(G_)[j_] << 16);           \
      atomicAdd(rp_ + j_, fv_);                                                \
    }                                                                          \
  } while (0)

#define CONSUME(KK, BUF, OFF, CNT, G, RL, VAL) do {                            \
    const ushort* kb_ = kernT + ((size_t)(KK) * 64 + q) * 32 + grp * 8;        \
    bf16x8 bf0_ = *(const bf16x8*)(kb_);                                       \
    bf16x8 bf1_ = *(const bf16x8*)(kb_ + 512);                                 \
    bf16x8 bf2_ = *(const bf16x8*)(kb_ + 1024);                                \
    bf16x8 bf3_ = *(const bf16x8*)(kb_ + 1536);                                \
    float* sp_ = &stage[wv][BUF][0][0];                                        \
    if (VAL) PRESUM8(G, RL, part);                                             \
    for (int off_ = 16; off_ < CNT; off_ += 16) {  /* rare: cnt>16 */          \
      bool v_ = (off_ + eidx < CNT);                                           \
      int ixT_ = OFF + off_ + (v_ ? eidx : 0);                                 \
      if (ixT_ >= ENTCAP) ixT_ = 0;                                            \
      uint32_t e_ = ents[wv][ixT_];                                            \
      if (v_) {                                                                \
        const ushort* fpT_ = feat16 + (size_t)(e_ & 0x3FFFFu) * CIN + part * 8;\
        u16x8 h_ = *(const u16x8*)fpT_;                                        \
        int rlT_ = (int)((e_ >> 18) & 15u);                                    \
        PRESUM8(h_, rlT_, part);                                               \
      }                                                                        \
    }                                                                          \
    asm volatile("s_waitcnt lgkmcnt(0)" ::: "memory");                         \
    const float* ar_ = sp_ + q * 36 + grp * 8;                                 \
    float4 u0_ = *(const float4*)ar_;                                          \
    float4 u1_ = *(const float4*)(ar_ + 4);                                    \
    bf16x8 af_;                                                                \
    uint32_t w0_ = cvtpk(u0_.x, u0_.y), w1_ = cvtpk(u0_.z, u0_.w);             \
    uint32_t w2_ = cvtpk(u1_.x, u1_.y), w3_ = cvtpk(u1_.z, u1_.w);             \
    af_[0] = (short)(w0_ & 0xFFFF); af_[1] = (short)(w0_ >> 16);               \
    af_[2] = (short)(w1_ & 0xFFFF); af_[3] = (short)(w1_ >> 16);               \
    af_[4] = (short)(w2_ & 0xFFFF); af_[5] = (short)(w2_ >> 16);               \
    af_[6] = (short)(w3_ & 0xFFFF); af_[7] = (short)(w3_ >> 16);               \
    acc0 = __builtin_amdgcn_mfma_f32_16x16x32_bf16(af_, bf0_, acc0, 0, 0, 0);  \
    acc1 = __builtin_amdgcn_mfma_f32_16x16x32_bf16(af_, bf1_, acc1, 0, 0, 0);  \
    acc2 = __builtin_amdgcn_mfma_f32_16x16x32_bf16(af_, bf2_, acc2, 0, 0, 0);  \
    acc3 = __builtin_amdgcn_mfma_f32_16x16x32_bf16(af_, bf3_, acc3, 0, 0, 0);  \
    asm volatile("s_waitcnt lgkmcnt(0)" ::: "memory");                         \
    float2* zp_ = (float2*)sp_;                                                \
    zp_[l] = z2; zp_[l + 64] = z2; zp_[l + 128] = z2;                          \
    zp_[l + 192] = z2;                                                         \
    if (l < 32) zp_[l + 256] = z2;                                             \
  } while (0)

__global__ __launch_bounds__(256, 4) void conv_mfma7(
    const ushort* __restrict__ feat16,    // [N][CIN] bf16
    const uint32_t* __restrict__ binned,  // [E] k-major
    const int* __restrict__ start,        // [NBIN+1] k-major
    const ushort* __restrict__ kernT,     // [KVOL][4][16][32] bf16
    const float* __restrict__ bias,       // [COUT]
    float* __restrict__ out,              // [N][COUT]
    int NB) {
  __shared__ float stage[WPG][2][RB16][36];   // 4.5KB/wave, padded
  __shared__ uint32_t ents[WPG][ENTCAP];      // 1.5KB/wave
  const int wv  = threadIdx.x >> 6;
  const int l   = threadIdx.x & 63;
  const int q   = l & 15;          // A-row / B-col / D-col
  const int grp = l >> 4;          // k-chunk / D-row group
  const int eidx = l >> 2;         // entry slot 0..15 (gather)
  const int part = l & 3;          // 16B chunk      (gather)
  const int blk = blockIdx.x * WPG + wv;
  const float2 z2 = {0.f, 0.f};

  // segment bounds (k-major, strided): lane j<27 holds [s_lo, s_hi)
  int s_lo = 0, s_hi = 0;
  if (l < KVOL) {
    s_lo = start[l * NB + blk];
    s_hi = start[l * NB + blk + 1];
  }
  int cnt_l = s_hi - s_lo;                       // 0 for l >= 27
  // inclusive prefix over lanes -> exclusive offsets into ents
  int pfx = cnt_l;
#pragma unroll
  for (int d = 1; d < 32; d <<= 1) { int u = __shfl_up(pfx, d); if (l >= d) pfx += u; }
  int excl = pfx - cnt_l;
  if (excl + cnt_l > ENTCAP) cnt_l = 0;          // statistically impossible; stay safe

  // copy all 27 segments into LDS (coalesced bursts, off critical path)
  for (int j = 0; j < KVOL; ++j) {
    int sj = __shfl(s_lo, j);
    int cj = __shfl(cnt_l, j);
    int oj = __shfl(excl, j);
    for (int i = l; i < cj; i += 64) ents[wv][oj + i] = binned[sj + i];
  }

  // zero both staging buffers (1152 floats)
  {
    float2* zp = (float2*)&stage[wv][0][0][0];
#pragma unroll
    for (int i = 0; i < 9; ++i) zp[l + i * 64] = z2;
  }

  float bv0 = bias[q], bv1 = bias[16 + q], bv2 = bias[32 + q], bv3 = bias[48 + q];

  asm volatile("s_waitcnt lgkmcnt(0)" ::: "memory");   // copy + zero visible
  __builtin_amdgcn_sched_barrier(0);

  f32x4 acc0 = {0,0,0,0}, acc1 = {0,0,0,0}, acc2 = {0,0,0,0}, acc3 = {0,0,0,0};
  int offA, cntA, rlA; bool valA; u16x8 gA = {0,0,0,0,0,0,0,0};
  int offB, cntB, rlB; bool valB; u16x8 gB = {0,0,0,0,0,0,0,0};

  STAGE(0, offA, cntA, gA, rlA, valA);
  for (int k = 0; k < KVOL - 1; k += 2) {
    STAGE(k + 1, offB, cntB, gB, rlB, valB);
    CONSUME(k, 0, offA, cntA, gA, rlA, valA);
    STAGE(k + 2, offA, cntA, gA, rlA, valA);
    CONSUME(k + 1, 1, offB, cntB, gB, rlB, valB);
  }
  CONSUME(KVOL - 1, 0, offA, cntA, gA, rlA, valA);

  // epilogue: D col=q, row=grp*4+reg; rows disjoint across waves -> plain stores
  const int R0 = blk * RB16;
#pragma unroll
  for (int reg = 0; reg < 4; ++reg) {
    float* op = out + (size_t)(R0 + grp * 4 + reg) * COUT + q;
    op[0]  = acc0[reg] + bv0;
    op[16] = acc1[reg] + bv1;
    op[32] = acc2[reg] + bv2;
    op[48] = acc3[reg] + bv3;
  }
}

// ---------------------------------------------------------------------------
extern "C" void kernel_launch(void* const* d_in, const int* in_sizes, int n_in,
                              void* d_out, int out_size, void* d_ws, size_t ws_size,
                              hipStream_t stream) {
  const float* feat  = (const float*)d_in[0];
  const int4*  kmap2 = (const int4*)d_in[3];   // 2 pairs per int4
  const float* kern  = (const float*)d_in[4];
  const float* bias  = (const float*)d_in[5];
  float* out = (float*)d_out;

  const int N = in_sizes[0] / CIN;            // 200000
  const int M = in_sizes[3] / (2 * KVOL);     // 100000
  const int M2 = M / 2;                       // 50000
  const int NB = N / RB16;                    // 12500
  const int NBIN = NB * KVOL;                 // 337500

  // workspace
  ushort* feat16 = (ushort*)d_ws;                       // N*CIN bf16 (12.8MB)
  ushort* kernT  = feat16 + (size_t)N * CIN;            // 55296 ushorts
  int* count   = (int*)(kernT + (size_t)KVOL * CIN * COUT);
  int* startA  = count + NBIN;                          // NBIN+1
  int* cursor  = startA + NBIN + 1;
  int* partial = cursor + NBIN;                         // 128
  uint32_t* binned = (uint32_t*)(partial + 128);        // KVOL*M

  const int nchunks = (NBIN + SCAN_CHUNK - 1) / SCAN_CHUNK;   // 83

  hipMemsetAsync(count, 0, (size_t)NBIN * sizeof(int), stream);
  hipLaunchKernelGGL(feat_cvt_kernel, dim3((N * CIN / 4 + 255) / 256), dim3(256), 0, stream,
                     feat, feat16, N * CIN / 4);
  hipLaunchKernelGGL(kern_cvt_kernel, dim3(KVOL), dim3(256), 0, stream, kern, kernT);

  dim3 pgrid((M2 + 255) / 256, KVOL);
  hipLaunchKernelGGL(hist_kernel, pgrid, dim3(256), 0, stream, kmap2, count, M2, NB);
  hipLaunchKernelGGL(scan_reduce, dim3(nchunks), dim3(256), 0, stream, count, partial, NBIN);
  hipLaunchKernelGGL(scan_partials, dim3(1), dim3(64), 0, stream, partial, nchunks, startA + NBIN);
  hipLaunchKernelGGL(scan_down, dim3(nchunks), dim3(256), 0, stream,
                     count, partial, startA, cursor, NBIN);
  hipLaunchKernelGGL(scatter_kernel, pgrid, dim3(256), 0, stream, kmap2, cursor, binned, M2, NB);

  hipLaunchKernelGGL(conv_mfma7, dim3(NB / WPG), dim3(256), 0, stream,
                     feat16, binned, startA, kernT, bias, out, NB);
}